// Round 1
// baseline (2147.432 us; speedup 1.0000x reference)
//
#include <hip/hip_runtime.h>
#include <hip/hip_fp16.h>
#include <math.h>

// Problem dims
#define TT 256
#define BB 64
#define DD 512
#define HH 512
#define NC 2048  // 4 gates * H, col = j*4+g (g: 0=i,1=f,2=o,3=ctilde)

// Workspace layout (float-slot offsets).
#define AH_OFF   0ull          // f16 [16384][1024]  (xt | m), row = t*64+b
#define DLH_OFF  8388608ull    // f16 [16384][512]   Dl
#define DH_OFF   12582912ull   // f32 [16384][512]   delta_h
#define GP_OFF   20971520ull   // f16 [16384][2048]  G_pre
#define WCT_OFF  37748736ull   // f16 [2048][1024]   gate W (x|m), col-major rows
#define GHT_OFF  38797312ull   // f16 [512][512]     gh_W transposed
#define WHT_OFF  38928384ull   // f16 [2048][512]    gate W h-part, col-major rows
#define BC_OFF   39452672ull   // f32 [2048]
#define HS_OFF   39454720ull   // uint [2][4 groups][4096] frag-linear h exchange
#define FLG_OFF  39487488ull   // int [4 groups][64] per-WAVE flags (member*8+wave)

typedef _Float16 h8_t __attribute__((ext_vector_type(8)));
typedef _Float16 h4_t __attribute__((ext_vector_type(4)));
typedef float f32x4 __attribute__((ext_vector_type(4)));
typedef unsigned long long ull2_t __attribute__((ext_vector_type(2)));

typedef const __attribute__((address_space(1))) void* gas_p;
typedef __attribute__((address_space(3))) void* las_p;

__device__ __forceinline__ float fast_exp2(float x) {
#if defined(__has_builtin)
#if __has_builtin(__builtin_amdgcn_exp2f)
  return __builtin_amdgcn_exp2f(x);
#else
  return exp2f(x);
#endif
#else
  return exp2f(x);
#endif
}
__device__ __forceinline__ float fast_rcp(float x) {
#if defined(__has_builtin)
#if __has_builtin(__builtin_amdgcn_rcpf)
  return __builtin_amdgcn_rcpf(x);
#else
  return 1.0f / x;
#endif
#else
  return 1.0f / x;
#endif
}
#define LOG2E 1.4426950408889634f
__device__ __forceinline__ float sigmoidf_(float v) {
  return fast_rcp(1.0f + fast_exp2(-LOG2E * v));
}
__device__ __forceinline__ float tanhf_(float v) {
  return 1.0f - 2.0f * fast_rcp(1.0f + fast_exp2(2.0f * LOG2E * v));
}

// ---------------------------------------------------------------------------
// Repack:
//   WCT f16 [2048][1024]: WCT[4j+g][k<512]=Wg[k][j] (x), [512+k]=Wg[1024+k][j] (m)
//   WHT f16 [2048][512] :  WHT[4j+g][k] = Wg[512+k][j]
//   GHT f16 [512][512]  :  GHT[j][k] = ghW[k][j]
//   BC  f32 [2048]
// ---------------------------------------------------------------------------
__global__ __launch_bounds__(256) void repack_kernel(
    const float* __restrict__ Wi, const float* __restrict__ bi,
    const float* __restrict__ Wf, const float* __restrict__ bff,
    const float* __restrict__ Wo, const float* __restrict__ bo,
    const float* __restrict__ Wc, const float* __restrict__ bc,
    const float* __restrict__ ghW,
    __half* __restrict__ WCT, __half* __restrict__ WHT,
    __half* __restrict__ GHT, float* __restrict__ BC) {
  int idx = blockIdx.x * 256 + threadIdx.x;  // 512*512
  int k = idx >> 9, j = idx & 511;
  const float* Ws[4] = {Wi, Wf, Wo, Wc};
  const float* bs[4] = {bi, bff, bo, bc};
#pragma unroll
  for (int g = 0; g < 4; ++g) {
    const float* W = Ws[g];
    int col = j * 4 + g;
    WCT[(size_t)col * 1024 + k] = __float2half(W[(size_t)k * 512 + j]);
    WCT[(size_t)col * 1024 + 512 + k] = __float2half(W[(size_t)(1024 + k) * 512 + j]);
    WHT[(size_t)col * 512 + k] = __float2half(W[(size_t)(512 + k) * 512 + j]);
    if (k == 0) BC[col] = bs[g][j];
  }
  GHT[(size_t)j * 512 + k] = __float2half(ghW[(size_t)k * 512 + j]);
}

// ---------------------------------------------------------------------------
// xt: AH[r][d] = xt (f16), AH[r][512+d] = m (f16), DLh[r][d] = dl (f16)
// x layout: [B][4][T][D]; 0=X,1=Xl,2=M,3=Dl ; r = t*64+b
// ---------------------------------------------------------------------------
__global__ __launch_bounds__(256) void xt_kernel(
    const float* __restrict__ x, const float* __restrict__ Xmean,
    const float* __restrict__ gxw, const float* __restrict__ gxb,
    __half* __restrict__ AH, __half* __restrict__ DLh) {
  int idx = blockIdx.x * 256 + threadIdx.x;
  int d = (idx & 127) * 4;
  int r = idx >> 7;
  int b = r & 63, t = r >> 6;
  size_t base = (((size_t)b * 4) * TT + t) * DD + d;
  const float4 X = *(const float4*)&x[base];
  const float4 Xl = *(const float4*)&x[base + (size_t)TT * DD];
  const float4 M = *(const float4*)&x[base + 2ull * TT * DD];
  const float4 Dl = *(const float4*)&x[base + 3ull * TT * DD];
  const float4 xm = *(const float4*)&Xmean[(size_t)t * DD + d];
  const float4 gw = *(const float4*)&gxw[d];
  const float4 gb = *(const float4*)&gxb[d];
  float o[4];
  {
    float dx = fast_exp2(-LOG2E * fmaxf(0.f, Dl.x * gw.x + gb.x));
    o[0] = M.x * X.x + (1.f - M.x) * (dx * Xl.x + (1.f - dx) * xm.x);
  }
  {
    float dx = fast_exp2(-LOG2E * fmaxf(0.f, Dl.y * gw.y + gb.y));
    o[1] = M.y * X.y + (1.f - M.y) * (dx * Xl.y + (1.f - dx) * xm.y);
  }
  {
    float dx = fast_exp2(-LOG2E * fmaxf(0.f, Dl.z * gw.z + gb.z));
    o[2] = M.z * X.z + (1.f - M.z) * (dx * Xl.z + (1.f - dx) * xm.z);
  }
  {
    float dx = fast_exp2(-LOG2E * fmaxf(0.f, Dl.w * gw.w + gb.w));
    o[3] = M.w * X.w + (1.f - M.w) * (dx * Xl.w + (1.f - dx) * xm.w);
  }
  h4_t xo = {(_Float16)o[0], (_Float16)o[1], (_Float16)o[2], (_Float16)o[3]};
  h4_t mo = {(_Float16)M.x, (_Float16)M.y, (_Float16)M.z, (_Float16)M.w};
  h4_t dlo = {(_Float16)Dl.x, (_Float16)Dl.y, (_Float16)Dl.z, (_Float16)Dl.w};
  *(h4_t*)&AH[(size_t)r * 1024 + d] = xo;
  *(h4_t*)&AH[(size_t)r * 1024 + 512 + d] = mo;
  *(h4_t*)&DLh[(size_t)r * 512 + d] = dlo;
}

// ---------------------------------------------------------------------------
// f16 MFMA GEMM, m97 structure: 128x128 tile, 256 threads, K-step 32,
// linear LDS [128][32] staged via global_load_lds width=16 (4 issues/thread).
// mode 0: C f16. mode 1: C f32, exp(-relu(v)).
// ---------------------------------------------------------------------------
__global__ __launch_bounds__(256, 2) void gemm16(
    const __half* __restrict__ A, const __half* __restrict__ BT,
    const float* __restrict__ bias, void* __restrict__ C,
    int K, int Ncols, int mode) {
  __shared__ _Float16 Ash[128 * 32];
  __shared__ _Float16 Bsh[128 * 32];
  const int tid = threadIdx.x;
  const int lane = tid & 63, w = tid >> 6;
  const int l15 = lane & 15, quad = lane >> 4;
  const int wr = w >> 1, wc = w & 1;
  const int row0 = blockIdx.y * 128, col0 = blockIdx.x * 128;

  f32x4 acc[4][4] = {};

  // staging chunk ci covers LDS bytes [ci*16, ci*16+16) == row ci>>2, halves (ci&3)*8
  const int ci0 = tid, ci1 = 256 + tid;
  const int ar0 = ci0 >> 2, ac0 = (ci0 & 3) * 8;
  const int ar1 = ci1 >> 2, ac1 = (ci1 & 3) * 8;
  const __half* Abase = A + (size_t)row0 * K;
  const __half* Bbase = BT + (size_t)col0 * K;

  for (int k0 = 0; k0 < K; k0 += 32) {
    __syncthreads();  // previous tile's readers done
    __builtin_amdgcn_global_load_lds((gas_p)(Abase + (size_t)ar0 * K + k0 + ac0),
                                     (las_p)(Ash + ci0 * 8), 16, 0, 0);
    __builtin_amdgcn_global_load_lds((gas_p)(Abase + (size_t)ar1 * K + k0 + ac1),
                                     (las_p)(Ash + ci1 * 8), 16, 0, 0);
    __builtin_amdgcn_global_load_lds((gas_p)(Bbase + (size_t)ar0 * K + k0 + ac0),
                                     (las_p)(Bsh + ci0 * 8), 16, 0, 0);
    __builtin_amdgcn_global_load_lds((gas_p)(Bbase + (size_t)ar1 * K + k0 + ac1),
                                     (las_p)(Bsh + ci1 * 8), 16, 0, 0);
    __syncthreads();  // vmcnt(0) drain -> tiles resident
    h8_t af[4], bf[4];
#pragma unroll
    for (int mt = 0; mt < 4; ++mt)
      af[mt] = *(const h8_t*)&Ash[(wr * 64 + mt * 16 + l15) * 32 + quad * 8];
#pragma unroll
    for (int ct = 0; ct < 4; ++ct)
      bf[ct] = *(const h8_t*)&Bsh[(wc * 64 + ct * 16 + l15) * 32 + quad * 8];
#pragma unroll
    for (int mt = 0; mt < 4; ++mt)
#pragma unroll
      for (int ct = 0; ct < 4; ++ct)
        acc[mt][ct] = __builtin_amdgcn_mfma_f32_16x16x32_f16(af[mt], bf[ct], acc[mt][ct], 0, 0, 0);
  }

#pragma unroll
  for (int ct = 0; ct < 4; ++ct) {
    const int col = col0 + wc * 64 + ct * 16 + l15;
    const float bv = bias[col];
#pragma unroll
    for (int mt = 0; mt < 4; ++mt) {
#pragma unroll
      for (int reg = 0; reg < 4; ++reg) {
        const int row = row0 + wr * 64 + mt * 16 + quad * 4 + reg;
        float v = acc[mt][ct][reg] + bv;
        if (mode == 0) {
          ((__half*)C)[(size_t)row * Ncols + col] = __float2half(v);
        } else {
          ((float*)C)[(size_t)row * Ncols + col] = fast_exp2(-LOG2E * fmaxf(0.f, v));
        }
      }
    }
  }
}

// ---------------------------------------------------------------------------
// Recurrence: 32 blocks x 512 threads, cooperative. 4 groups of 8 blocks.
// Group g owns rows [16g,16g+16); member m owns gate cols [256m,256m+256).
// WH in register B-fragments; h exchange in global, MFMA-A-frag-linear order.
// Sync redesign (this round): PER-WAVE flags (group g uses flg[g*64 + mem*8+w]).
// Each wave: exchange stores -> s_waitcnt vmcnt(0) -> flag -> out stores.
// No second __syncthreads; the first barrier is lgkmcnt-only so the GPh/DH
// epilogue streams stay in flight across it. Safety: flag(t+1) is set only
// after the wave's gbuf reads + A-frag loads of step t completed, and the
// poll requires all 64 group-wave flags (own block included) — so gbuf WAR
// and exchange double-buffer WAR remain ordered exactly as before.
// ---------------------------------------------------------------------------
__global__ __launch_bounds__(512, 2) void persist_rnn(
    const __half* __restrict__ GPh, const float* __restrict__ DH,
    const __half* __restrict__ WHT, unsigned* __restrict__ hs,
    int* __restrict__ flg, float* __restrict__ out) {
  __shared__ __align__(16) float gbuf[16 * 260];
  const int g = blockIdx.x & 3;   // group
  const int m = blockIdx.x >> 2;  // member 0..7
  const int tid = threadIdx.x;
  const int lane = tid & 63;
  const int w = tid >> 6;
  const int l15 = lane & 15;
  const int quad = lane >> 4;
  const int rowg0 = g << 4;

  // ---- B fragments, loaded once ----
  h8_t bfrag[2][16];
  const int colbase = (m << 8) + (w << 5);
#pragma unroll
  for (int nt = 0; nt < 2; ++nt) {
#pragma unroll
    for (int kt = 0; kt < 16; ++kt) {
      int col = colbase + nt * 16 + l15;
      int k = kt * 32 + quad * 8;
      bfrag[nt][kt] = *(const h8_t*)&WHT[(size_t)col * 512 + k];
    }
  }

  const int r_ep = w;
  const int ug = (m << 6) + lane;
  // frag-layout dest uint indices for the two h stores (even lanes use them)
  const int ktu = ug >> 5, q3 = (ug >> 3) & 3, qi = (ug & 7) >> 1;
  const int d0 = ktu * 256 + (q3 * 16 + r_ep) * 4 + qi;
  const int d1 = ktu * 256 + (q3 * 16 + r_ep + 8) * 4 + qi;
  const int myflag = (g << 6) + (m << 3) + w;

  float c0 = 0.f, c1 = 0.f;

  for (int t = 0; t < TT; ++t) {
    // ---- per-wave poll: 64 flags of the group, one per lane ----
    if (t > 0) {
      const int* fb = flg + (g << 6);
      for (;;) {
        int v = __hip_atomic_load(&fb[lane], __ATOMIC_RELAXED,
                                  __HIP_MEMORY_SCOPE_AGENT);
        if (__all(v >= t)) break;
        __builtin_amdgcn_s_sleep(1);
      }
    }

    // ---- A fragments straight from L3 (frag-linear layout) ----
    const unsigned long long* hsp =
        (const unsigned long long*)hs + ((size_t)(t & 1) * 4 + g) * 2048;
    h8_t af[16];
#pragma unroll
    for (int kt = 0; kt < 16; ++kt) {
      unsigned long long a = __hip_atomic_load(&hsp[kt * 128 + lane * 2],
                                               __ATOMIC_RELAXED,
                                               __HIP_MEMORY_SCOPE_AGENT);
      unsigned long long b = __hip_atomic_load(&hsp[kt * 128 + lane * 2 + 1],
                                               __ATOMIC_RELAXED,
                                               __HIP_MEMORY_SCOPE_AGENT);
      ull2_t u2 = {a, b};
      af[kt] = __builtin_bit_cast(h8_t, u2);
    }

    // ---- epilogue operand streams issued AFTER the A-loads: vmcnt retires
    // in issue order, so the MFMA-operand waits are not gated by HBM latency.
    const h4_t gha = *(const h4_t*)&GPh[((size_t)t * 64 + rowg0 + r_ep) * NC + (ug << 2)];
    const h4_t ghb = *(const h4_t*)&GPh[((size_t)t * 64 + rowg0 + r_ep + 8) * NC + (ug << 2)];
    const int tn = (t + 1 < TT) ? t + 1 : t;
    const float dha = DH[((size_t)tn * 64 + rowg0 + r_ep) * HH + ug];
    const float dhb = DH[((size_t)tn * 64 + rowg0 + r_ep + 8) * HH + ug];

    // ---- MFMA ----
    f32x4 acc0 = {0.f, 0.f, 0.f, 0.f};
    f32x4 acc1 = {0.f, 0.f, 0.f, 0.f};
#pragma unroll
    for (int kt = 0; kt < 16; ++kt) {
      acc0 = __builtin_amdgcn_mfma_f32_16x16x32_f16(af[kt], bfrag[0][kt], acc0, 0, 0, 0);
      acc1 = __builtin_amdgcn_mfma_f32_16x16x32_f16(af[kt], bfrag[1][kt], acc1, 0, 0, 0);
    }
#pragma unroll
    for (int reg = 0; reg < 4; ++reg) {
      int row = quad * 4 + reg;
      gbuf[row * 260 + (w << 5) + l15] = acc0[reg];
      gbuf[row * 260 + (w << 5) + 16 + l15] = acc1[reg];
    }
    // ---- light barrier: LDS drain only; GPh/DH loads may stay in flight ----
    asm volatile("s_waitcnt lgkmcnt(0)" ::: "memory");
    __builtin_amdgcn_s_barrier();
    asm volatile("" ::: "memory");

    // ---- epilogue: rows r_ep, r_ep+8 ; unit ug ----
    float h0v, h1v;
    {
      const float4 gv = *(const float4*)&gbuf[r_ep * 260 + (lane << 2)];
      float ig = sigmoidf_(gv.x + (float)gha[0]);
      float fg = sigmoidf_(gv.y + (float)gha[1]);
      float og = sigmoidf_(gv.z + (float)gha[2]);
      float ct = tanhf_(gv.w + (float)gha[3]);
      c0 = fg * c0 + ig * ct;
      h0v = og * tanhf_(c0);
    }
    {
      const float4 gv = *(const float4*)&gbuf[(r_ep + 8) * 260 + (lane << 2)];
      float ig = sigmoidf_(gv.x + (float)ghb[0]);
      float fg = sigmoidf_(gv.y + (float)ghb[1]);
      float og = sigmoidf_(gv.z + (float)ghb[2]);
      float ct = tanhf_(gv.w + (float)ghb[3]);
      c1 = fg * c1 + ig * ct;
      h1v = og * tanhf_(c1);
    }

    if (t + 1 < TT) {
      unsigned* hsn = hs + ((size_t)((t + 1) & 1) * 4 + g) * 4096;
      unsigned short hb0 = __half_as_ushort(__float2half(dha * h0v));
      unsigned o0 = (unsigned)__shfl_xor((int)(unsigned)hb0, 1) & 0xffffu;
      unsigned short hb1 = __half_as_ushort(__float2half(dhb * h1v));
      unsigned o1 = (unsigned)__shfl_xor((int)(unsigned)hb1, 1) & 0xffffu;
      if (!(lane & 1)) {
        __hip_atomic_store(&hsn[d0], (unsigned)hb0 | (o0 << 16), __ATOMIC_RELAXED,
                           __HIP_MEMORY_SCOPE_AGENT);
        __hip_atomic_store(&hsn[d1], (unsigned)hb1 | (o1 << 16), __ATOMIC_RELAXED,
                           __HIP_MEMORY_SCOPE_AGENT);
      }
      // per-wave publish: drain only this wave's exchange stores, then flag.
      asm volatile("s_waitcnt vmcnt(0)" ::: "memory");
      if (lane == 0)
        __hip_atomic_store(&flg[myflag], t + 1, __ATOMIC_RELAXED,
                           __HIP_MEMORY_SCOPE_AGENT);
    }

    // result stores kept OFF the publish path
    out[((size_t)(rowg0 + r_ep) * TT + t) * HH + ug] = h0v;
    out[((size_t)(rowg0 + r_ep + 8) * TT + t) * HH + ug] = h1v;
  }
}

// ---------------------------------------------------------------------------
extern "C" void kernel_launch(void* const* d_in, const int* in_sizes, int n_in,
                              void* d_out, int out_size, void* d_ws,
                              size_t ws_size, hipStream_t stream) {
  const float* x = (const float*)d_in[0];
  const float* Xmean = (const float*)d_in[1];
  const float* Wi = (const float*)d_in[2];
  const float* bi = (const float*)d_in[3];
  const float* Wf = (const float*)d_in[4];
  const float* bf = (const float*)d_in[5];
  const float* Wo = (const float*)d_in[6];
  const float* bo = (const float*)d_in[7];
  const float* Wc = (const float*)d_in[8];
  const float* bc = (const float*)d_in[9];
  const float* gxw = (const float*)d_in[10];
  const float* gxb = (const float*)d_in[11];
  const float* ghW = (const float*)d_in[12];
  const float* ghb = (const float*)d_in[13];
  float* out = (float*)d_out;
  float* ws = (float*)d_ws;

  __half* AH = (__half*)(ws + AH_OFF);
  __half* DLh = (__half*)(ws + DLH_OFF);
  float* DH = ws + DH_OFF;
  __half* GPh = (__half*)(ws + GP_OFF);
  __half* WCT = (__half*)(ws + WCT_OFF);
  __half* GHT = (__half*)(ws + GHT_OFF);
  __half* WHT = (__half*)(ws + WHT_OFF);
  float* BC = ws + BC_OFF;
  unsigned* HS = (unsigned*)(ws + HS_OFF);
  int* FLG = (int*)(ws + FLG_OFF);

  // zero h exchange buffers + 256 per-wave flags (ws poisoned each launch)
  hipMemsetAsync(HS, 0, (2ull * 4 * 4096 + 256) * sizeof(unsigned), stream);

  repack_kernel<<<1024, 256, 0, stream>>>(Wi, bi, Wf, bf, Wo, bo, Wc, bc, ghW,
                                          WCT, WHT, GHT, BC);
  xt_kernel<<<8192, 256, 0, stream>>>(x, Xmean, gxw, gxb, AH, DLh);
  // DH = exp(-relu(Dl @ ghW + ghb)) : M=16384, N=512, K=512
  gemm16<<<dim3(4, 128), 256, 0, stream>>>(DLh, GHT, ghb, (void*)DH, 512, 512, 1);
  // GP = [xt|m] @ [Wx;Wm] + BC : M=16384, N=2048, K=1024 (f16 out)
  gemm16<<<dim3(16, 128), 256, 0, stream>>>(AH, WCT, BC, (void*)GPh, 1024, NC, 0);

  void* args[] = {(void*)&GPh, (void*)&DH, (void*)&WHT,
                  (void*)&HS, (void*)&FLG, (void*)&out};
  hipLaunchCooperativeKernel((const void*)persist_rnn, dim3(32), dim3(512),
                             args, 0, stream);
}

// Round 4
// 1557.697 us; speedup vs baseline: 1.3786x; 1.3786x over previous
//
#include <hip/hip_runtime.h>
#include <hip/hip_fp16.h>
#include <math.h>

// Problem dims
#define TT 256
#define BB 64
#define DD 512
#define HH 512
#define NC 2048  // 4 gates * H, col = j*4+g (g: 0=i,1=f,2=o,3=ctilde)

// Workspace layout (float-slot offsets).
#define AH_OFF   0ull          // f16 [16384][1024]  (xt | m), row = t*64+b
#define DLH_OFF  8388608ull    // f16 [16384][512]   Dl
#define DH_OFF   12582912ull   // f32 [16384][512]   delta_h
#define GP_OFF   20971520ull   // f16 [16384][2048]  G_pre
#define WCT_OFF  37748736ull   // f16 [2048][1024]   gate W (x|m), col-major rows
#define GHT_OFF  38797312ull   // f16 [512][512]     gh_W transposed
#define WHT_OFF  38928384ull   // f16 [2048][512]    gate W h-part, col-major rows
#define BC_OFF   39452672ull   // f32 [2048]
#define HS_OFF   39454720ull   // uint [2][4 groups][4096] frag-linear h exchange
#define FLG_OFF  39487488ull   // int [32] flags (4 groups x 8, packed)

typedef _Float16 h8_t __attribute__((ext_vector_type(8)));
typedef _Float16 h4_t __attribute__((ext_vector_type(4)));
typedef float f32x4 __attribute__((ext_vector_type(4)));
typedef unsigned long long ull2_t __attribute__((ext_vector_type(2)));

typedef const __attribute__((address_space(1))) void* gas_p;
typedef __attribute__((address_space(3))) void* las_p;

__device__ __forceinline__ float fast_exp2(float x) {
#if defined(__has_builtin)
#if __has_builtin(__builtin_amdgcn_exp2f)
  return __builtin_amdgcn_exp2f(x);
#else
  return exp2f(x);
#endif
#else
  return exp2f(x);
#endif
}
__device__ __forceinline__ float fast_rcp(float x) {
#if defined(__has_builtin)
#if __has_builtin(__builtin_amdgcn_rcpf)
  return __builtin_amdgcn_rcpf(x);
#else
  return 1.0f / x;
#endif
#else
  return 1.0f / x;
#endif
}
#define LOG2E 1.4426950408889634f
__device__ __forceinline__ float sigmoidf_(float v) {
  return fast_rcp(1.0f + fast_exp2(-LOG2E * v));
}
__device__ __forceinline__ float tanhf_(float v) {
  return 1.0f - 2.0f * fast_rcp(1.0f + fast_exp2(2.0f * LOG2E * v));
}

// ---------------------------------------------------------------------------
// Repack:
//   WCT f16 [2048][1024]: WCT[4j+g][k<512]=Wg[k][j] (x), [512+k]=Wg[1024+k][j] (m)
//   WHT f16 [2048][512] :  WHT[4j+g][k] = Wg[512+k][j]
//   GHT f16 [512][512]  :  GHT[j][k] = ghW[k][j]
//   BC  f32 [2048]
// ---------------------------------------------------------------------------
__global__ __launch_bounds__(256) void repack_kernel(
    const float* __restrict__ Wi, const float* __restrict__ bi,
    const float* __restrict__ Wf, const float* __restrict__ bff,
    const float* __restrict__ Wo, const float* __restrict__ bo,
    const float* __restrict__ Wc, const float* __restrict__ bc,
    const float* __restrict__ ghW,
    __half* __restrict__ WCT, __half* __restrict__ WHT,
    __half* __restrict__ GHT, float* __restrict__ BC) {
  int idx = blockIdx.x * 256 + threadIdx.x;  // 512*512
  int k = idx >> 9, j = idx & 511;
  const float* Ws[4] = {Wi, Wf, Wo, Wc};
  const float* bs[4] = {bi, bff, bo, bc};
#pragma unroll
  for (int g = 0; g < 4; ++g) {
    const float* W = Ws[g];
    int col = j * 4 + g;
    WCT[(size_t)col * 1024 + k] = __float2half(W[(size_t)k * 512 + j]);
    WCT[(size_t)col * 1024 + 512 + k] = __float2half(W[(size_t)(1024 + k) * 512 + j]);
    WHT[(size_t)col * 512 + k] = __float2half(W[(size_t)(512 + k) * 512 + j]);
    if (k == 0) BC[col] = bs[g][j];
  }
  GHT[(size_t)j * 512 + k] = __float2half(ghW[(size_t)k * 512 + j]);
}

// ---------------------------------------------------------------------------
// xt: AH[r][d] = xt (f16), AH[r][512+d] = m (f16), DLh[r][d] = dl (f16)
// x layout: [B][4][T][D]; 0=X,1=Xl,2=M,3=Dl ; r = t*64+b
// ---------------------------------------------------------------------------
__global__ __launch_bounds__(256) void xt_kernel(
    const float* __restrict__ x, const float* __restrict__ Xmean,
    const float* __restrict__ gxw, const float* __restrict__ gxb,
    __half* __restrict__ AH, __half* __restrict__ DLh) {
  int idx = blockIdx.x * 256 + threadIdx.x;
  int d = (idx & 127) * 4;
  int r = idx >> 7;
  int b = r & 63, t = r >> 6;
  size_t base = (((size_t)b * 4) * TT + t) * DD + d;
  const float4 X = *(const float4*)&x[base];
  const float4 Xl = *(const float4*)&x[base + (size_t)TT * DD];
  const float4 M = *(const float4*)&x[base + 2ull * TT * DD];
  const float4 Dl = *(const float4*)&x[base + 3ull * TT * DD];
  const float4 xm = *(const float4*)&Xmean[(size_t)t * DD + d];
  const float4 gw = *(const float4*)&gxw[d];
  const float4 gb = *(const float4*)&gxb[d];
  float o[4];
  {
    float dx = fast_exp2(-LOG2E * fmaxf(0.f, Dl.x * gw.x + gb.x));
    o[0] = M.x * X.x + (1.f - M.x) * (dx * Xl.x + (1.f - dx) * xm.x);
  }
  {
    float dx = fast_exp2(-LOG2E * fmaxf(0.f, Dl.y * gw.y + gb.y));
    o[1] = M.y * X.y + (1.f - M.y) * (dx * Xl.y + (1.f - dx) * xm.y);
  }
  {
    float dx = fast_exp2(-LOG2E * fmaxf(0.f, Dl.z * gw.z + gb.z));
    o[2] = M.z * X.z + (1.f - M.z) * (dx * Xl.z + (1.f - dx) * xm.z);
  }
  {
    float dx = fast_exp2(-LOG2E * fmaxf(0.f, Dl.w * gw.w + gb.w));
    o[3] = M.w * X.w + (1.f - M.w) * (dx * Xl.w + (1.f - dx) * xm.w);
  }
  h4_t xo = {(_Float16)o[0], (_Float16)o[1], (_Float16)o[2], (_Float16)o[3]};
  h4_t mo = {(_Float16)M.x, (_Float16)M.y, (_Float16)M.z, (_Float16)M.w};
  h4_t dlo = {(_Float16)Dl.x, (_Float16)Dl.y, (_Float16)Dl.z, (_Float16)Dl.w};
  *(h4_t*)&AH[(size_t)r * 1024 + d] = xo;
  *(h4_t*)&AH[(size_t)r * 1024 + 512 + d] = mo;
  *(h4_t*)&DLh[(size_t)r * 512 + d] = dlo;
}

// ---------------------------------------------------------------------------
// f16 MFMA GEMM, m97 structure: 128x128 tile, 256 threads, K-step 32,
// linear LDS [128][32] staged via global_load_lds width=16 (4 issues/thread).
// mode 0: C f16. mode 1: C f32, exp(-relu(v)).  (proven correct in round 1)
// ---------------------------------------------------------------------------
__global__ __launch_bounds__(256, 2) void gemm16(
    const __half* __restrict__ A, const __half* __restrict__ BT,
    const float* __restrict__ bias, void* __restrict__ C,
    int K, int Ncols, int mode) {
  __shared__ _Float16 Ash[128 * 32];
  __shared__ _Float16 Bsh[128 * 32];
  const int tid = threadIdx.x;
  const int lane = tid & 63, w = tid >> 6;
  const int l15 = lane & 15, quad = lane >> 4;
  const int wr = w >> 1, wc = w & 1;
  const int row0 = blockIdx.y * 128, col0 = blockIdx.x * 128;

  f32x4 acc[4][4] = {};

  // staging chunk ci covers LDS bytes [ci*16, ci*16+16) == row ci>>2, halves (ci&3)*8
  const int ci0 = tid, ci1 = 256 + tid;
  const int ar0 = ci0 >> 2, ac0 = (ci0 & 3) * 8;
  const int ar1 = ci1 >> 2, ac1 = (ci1 & 3) * 8;
  const __half* Abase = A + (size_t)row0 * K;
  const __half* Bbase = BT + (size_t)col0 * K;

  for (int k0 = 0; k0 < K; k0 += 32) {
    __syncthreads();  // previous tile's readers done
    __builtin_amdgcn_global_load_lds((gas_p)(Abase + (size_t)ar0 * K + k0 + ac0),
                                     (las_p)(Ash + ci0 * 8), 16, 0, 0);
    __builtin_amdgcn_global_load_lds((gas_p)(Abase + (size_t)ar1 * K + k0 + ac1),
                                     (las_p)(Ash + ci1 * 8), 16, 0, 0);
    __builtin_amdgcn_global_load_lds((gas_p)(Bbase + (size_t)ar0 * K + k0 + ac0),
                                     (las_p)(Bsh + ci0 * 8), 16, 0, 0);
    __builtin_amdgcn_global_load_lds((gas_p)(Bbase + (size_t)ar1 * K + k0 + ac1),
                                     (las_p)(Bsh + ci1 * 8), 16, 0, 0);
    __syncthreads();  // vmcnt(0) drain -> tiles resident
    h8_t af[4], bf[4];
#pragma unroll
    for (int mt = 0; mt < 4; ++mt)
      af[mt] = *(const h8_t*)&Ash[(wr * 64 + mt * 16 + l15) * 32 + quad * 8];
#pragma unroll
    for (int ct = 0; ct < 4; ++ct)
      bf[ct] = *(const h8_t*)&Bsh[(wc * 64 + ct * 16 + l15) * 32 + quad * 8];
#pragma unroll
    for (int mt = 0; mt < 4; ++mt)
#pragma unroll
      for (int ct = 0; ct < 4; ++ct)
        acc[mt][ct] = __builtin_amdgcn_mfma_f32_16x16x32_f16(af[mt], bf[ct], acc[mt][ct], 0, 0, 0);
  }

#pragma unroll
  for (int ct = 0; ct < 4; ++ct) {
    const int col = col0 + wc * 64 + ct * 16 + l15;
    const float bv = bias[col];
#pragma unroll
    for (int mt = 0; mt < 4; ++mt) {
#pragma unroll
      for (int reg = 0; reg < 4; ++reg) {
        const int row = row0 + wr * 64 + mt * 16 + quad * 4 + reg;
        float v = acc[mt][ct][reg] + bv;
        if (mode == 0) {
          ((__half*)C)[(size_t)row * Ncols + col] = __float2half(v);
        } else {
          ((float*)C)[(size_t)row * Ncols + col] = fast_exp2(-LOG2E * fmaxf(0.f, v));
        }
      }
    }
  }
}

// ---------------------------------------------------------------------------
// Recurrence: 32 blocks x 512 threads, cooperative. 4 groups of 8 blocks.
// Group g owns rows [16g,16g+16); member m owns gate cols [256m,256m+256).
// WH in register B-fragments. h exchange buffer is stored in global memory in
// MFMA A-FRAGMENT-LINEAR order (per group): uint idx = kt*256 + lane*4 + q
// holds (row=lane&15, k=kt*32+(lane>>4)*8+2q+{0,1}). Waves load A-frags
// straight from L3 (agent-scope 8-B atomic loads, 1 KB/instr coalescing) —
// NO LDS staging. Sync: 2 __syncthreads/step + per-wave flag poll (all lanes
// read the group's 8 packed flags); flag set after the vm-drain barrier, so
// own-flag >= t+1 implies all of that block's reads/stores for step t done.
// (This is the round-0 protocol, hardware-proven at 1014us.)
//
// Local reorders vs round 0 (protocol-preserving):
//  (i)  A-frag loads issued BEFORE the GPh/DH epilogue streams: vmcnt retires
//       in issue order, so the MFMA operand wait stops being gated by the
//       ~900cy HBM loads (compiler can wait at vmcnt(4), leaving them in
//       flight through the MFMA phase).
//  (ii) out stores issued AFTER barrier-2 + flag publish: the pre-flag
//       vmcnt(0) drain no longer waits on 2 HBM stores; they retire during
//       the next step's poll/MFMA slack and are drained (long-retired) at the
//       next step's barriers. Final iteration's stores complete at kernel end.
// ---------------------------------------------------------------------------
__global__ __launch_bounds__(512, 2) void persist_rnn(
    const __half* __restrict__ GPh, const float* __restrict__ DH,
    const __half* __restrict__ WHT, unsigned* __restrict__ hs,
    int* __restrict__ flg, float* __restrict__ out) {
  __shared__ __align__(16) float gbuf[16 * 260];
  const int g = blockIdx.x & 3;   // group
  const int m = blockIdx.x >> 2;  // member 0..7
  const int tid = threadIdx.x;
  const int lane = tid & 63;
  const int w = tid >> 6;
  const int l15 = lane & 15;
  const int quad = lane >> 4;
  const int rowg0 = g << 4;

  // ---- B fragments, loaded once ----
  h8_t bfrag[2][16];
  const int colbase = (m << 8) + (w << 5);
#pragma unroll
  for (int nt = 0; nt < 2; ++nt) {
#pragma unroll
    for (int kt = 0; kt < 16; ++kt) {
      int col = colbase + nt * 16 + l15;
      int k = kt * 32 + quad * 8;
      bfrag[nt][kt] = *(const h8_t*)&WHT[(size_t)col * 512 + k];
    }
  }

  const int r_ep = w;
  const int ug = (m << 6) + lane;
  // frag-layout dest uint indices for the two h stores (even lanes use them)
  const int ktu = ug >> 5, q3 = (ug >> 3) & 3, qi = (ug & 7) >> 1;
  const int d0 = ktu * 256 + (q3 * 16 + r_ep) * 4 + qi;
  const int d1 = ktu * 256 + (q3 * 16 + r_ep + 8) * 4 + qi;

  float c0 = 0.f, c1 = 0.f;

  for (int t = 0; t < TT; ++t) {
    // ---- per-wave poll: wait until all 8 group flags >= t ----
    if (t > 0) {
      const int* fb = flg + (g << 3);
      for (;;) {
        int v = __hip_atomic_load(&fb[lane & 7], __ATOMIC_RELAXED,
                                  __HIP_MEMORY_SCOPE_AGENT);
        if (__all(v >= t)) break;
        __builtin_amdgcn_s_sleep(1);
      }
    }

    // ---- A fragments straight from L3 (frag-linear layout), issued FIRST ----
    const unsigned long long* hsp =
        (const unsigned long long*)hs + ((size_t)(t & 1) * 4 + g) * 2048;
    h8_t af[16];
#pragma unroll
    for (int kt = 0; kt < 16; ++kt) {
      unsigned long long a = __hip_atomic_load(&hsp[kt * 128 + lane * 2],
                                               __ATOMIC_RELAXED,
                                               __HIP_MEMORY_SCOPE_AGENT);
      unsigned long long b = __hip_atomic_load(&hsp[kt * 128 + lane * 2 + 1],
                                               __ATOMIC_RELAXED,
                                               __HIP_MEMORY_SCOPE_AGENT);
      ull2_t u2 = {a, b};
      af[kt] = __builtin_bit_cast(h8_t, u2);
    }

    // ---- epilogue operand streams (HBM), issued after the A-loads so they
    // stay in flight through the MFMA phase (in-order vmcnt) ----
    const h4_t gha = *(const h4_t*)&GPh[((size_t)t * 64 + rowg0 + r_ep) * NC + (ug << 2)];
    const h4_t ghb = *(const h4_t*)&GPh[((size_t)t * 64 + rowg0 + r_ep + 8) * NC + (ug << 2)];
    const int tn = (t + 1 < TT) ? t + 1 : t;
    const float dha = DH[((size_t)tn * 64 + rowg0 + r_ep) * HH + ug];
    const float dhb = DH[((size_t)tn * 64 + rowg0 + r_ep + 8) * HH + ug];

    // ---- MFMA ----
    f32x4 acc0 = {0.f, 0.f, 0.f, 0.f};
    f32x4 acc1 = {0.f, 0.f, 0.f, 0.f};
#pragma unroll
    for (int kt = 0; kt < 16; ++kt) {
      acc0 = __builtin_amdgcn_mfma_f32_16x16x32_f16(af[kt], bfrag[0][kt], acc0, 0, 0, 0);
      acc1 = __builtin_amdgcn_mfma_f32_16x16x32_f16(af[kt], bfrag[1][kt], acc1, 0, 0, 0);
    }
#pragma unroll
    for (int reg = 0; reg < 4; ++reg) {
      int row = quad * 4 + reg;
      gbuf[row * 260 + (w << 5) + l15] = acc0[reg];
      gbuf[row * 260 + (w << 5) + 16 + l15] = acc1[reg];
    }
    __syncthreads();

    // ---- epilogue: rows r_ep, r_ep+8 ; unit ug ----
    float h0v, h1v;
    {
      const float4 gv = *(const float4*)&gbuf[r_ep * 260 + (lane << 2)];
      float ig = sigmoidf_(gv.x + (float)gha[0]);
      float fg = sigmoidf_(gv.y + (float)gha[1]);
      float og = sigmoidf_(gv.z + (float)gha[2]);
      float ct = tanhf_(gv.w + (float)gha[3]);
      c0 = fg * c0 + ig * ct;
      h0v = og * tanhf_(c0);
    }
    {
      const float4 gv = *(const float4*)&gbuf[(r_ep + 8) * 260 + (lane << 2)];
      float ig = sigmoidf_(gv.x + (float)ghb[0]);
      float fg = sigmoidf_(gv.y + (float)ghb[1]);
      float og = sigmoidf_(gv.z + (float)ghb[2]);
      float ct = tanhf_(gv.w + (float)ghb[3]);
      c1 = fg * c1 + ig * ct;
      h1v = og * tanhf_(c1);
    }

    // ---- publish h for step t+1 (exchange stores BEFORE barrier-2 so the
    // barrier's vmcnt(0) drain covers them for the flag) ----
    if (t + 1 < TT) {
      unsigned* hsn = hs + ((size_t)((t + 1) & 1) * 4 + g) * 4096;
      unsigned short hb0 = __half_as_ushort(__float2half(dha * h0v));
      unsigned o0 = (unsigned)__shfl_xor((int)(unsigned)hb0, 1) & 0xffffu;
      unsigned short hb1 = __half_as_ushort(__float2half(dhb * h1v));
      unsigned o1 = (unsigned)__shfl_xor((int)(unsigned)hb1, 1) & 0xffffu;
      if (!(lane & 1)) {
        __hip_atomic_store(&hsn[d0], (unsigned)hb0 | (o0 << 16), __ATOMIC_RELAXED,
                           __HIP_MEMORY_SCOPE_AGENT);
        __hip_atomic_store(&hsn[d1], (unsigned)hb1 | (o1 << 16), __ATOMIC_RELAXED,
                           __HIP_MEMORY_SCOPE_AGENT);
      }
    }

    // ---- vm-drain barrier, then publish flag ----
    __syncthreads();  // compiler emits s_waitcnt vmcnt(0) per wave before barrier
    if (t + 1 < TT && tid == 0)
      __hip_atomic_store(&flg[(g << 3) + m], t + 1, __ATOMIC_RELAXED,
                         __HIP_MEMORY_SCOPE_AGENT);

    // ---- result stores OFF the publish path (drained next step / kernel end)
    out[((size_t)(rowg0 + r_ep) * TT + t) * HH + ug] = h0v;
    out[((size_t)(rowg0 + r_ep + 8) * TT + t) * HH + ug] = h1v;
  }
}

// ---------------------------------------------------------------------------
extern "C" void kernel_launch(void* const* d_in, const int* in_sizes, int n_in,
                              void* d_out, int out_size, void* d_ws,
                              size_t ws_size, hipStream_t stream) {
  const float* x = (const float*)d_in[0];
  const float* Xmean = (const float*)d_in[1];
  const float* Wi = (const float*)d_in[2];
  const float* bi = (const float*)d_in[3];
  const float* Wf = (const float*)d_in[4];
  const float* bf = (const float*)d_in[5];
  const float* Wo = (const float*)d_in[6];
  const float* bo = (const float*)d_in[7];
  const float* Wc = (const float*)d_in[8];
  const float* bc = (const float*)d_in[9];
  const float* gxw = (const float*)d_in[10];
  const float* gxb = (const float*)d_in[11];
  const float* ghW = (const float*)d_in[12];
  const float* ghb = (const float*)d_in[13];
  float* out = (float*)d_out;
  float* ws = (float*)d_ws;

  __half* AH = (__half*)(ws + AH_OFF);
  __half* DLh = (__half*)(ws + DLH_OFF);
  float* DH = ws + DH_OFF;
  __half* GPh = (__half*)(ws + GP_OFF);
  __half* WCT = (__half*)(ws + WCT_OFF);
  __half* GHT = (__half*)(ws + GHT_OFF);
  __half* WHT = (__half*)(ws + WHT_OFF);
  float* BC = ws + BC_OFF;
  unsigned* HS = (unsigned*)(ws + HS_OFF);
  int* FLG = (int*)(ws + FLG_OFF);

  // zero h exchange buffers + flags (ws poisoned each launch)
  hipMemsetAsync(HS, 0, (2ull * 4 * 4096 + 64) * sizeof(unsigned), stream);

  repack_kernel<<<1024, 256, 0, stream>>>(Wi, bi, Wf, bf, Wo, bo, Wc, bc, ghW,
                                          WCT, WHT, GHT, BC);
  xt_kernel<<<8192, 256, 0, stream>>>(x, Xmean, gxw, gxb, AH, DLh);
  // DH = exp(-relu(Dl @ ghW + ghb)) : M=16384, N=512, K=512
  gemm16<<<dim3(4, 128), 256, 0, stream>>>(DLh, GHT, ghb, (void*)DH, 512, 512, 1);
  // GP = [xt|m] @ [Wx;Wm] + BC : M=16384, N=2048, K=1024 (f16 out)
  gemm16<<<dim3(16, 128), 256, 0, stream>>>(AH, WCT, BC, (void*)GPh, 1024, NC, 0);

  void* args[] = {(void*)&GPh, (void*)&DH, (void*)&WHT,
                  (void*)&HS, (void*)&FLG, (void*)&out};
  hipLaunchCooperativeKernel((const void*)persist_rnn, dim3(32), dim3(512),
                             args, 0, stream);
}

// Round 5
// 1046.405 us; speedup vs baseline: 2.0522x; 1.4886x over previous
//
#include <hip/hip_runtime.h>
#include <hip/hip_fp16.h>
#include <math.h>

// Problem dims
#define TT 256
#define BB 64
#define DD 512
#define HH 512
#define NC 2048  // 4 gates * H, col = j*4+g (g: 0=i,1=f,2=o,3=ctilde)

// Workspace layout (float-slot offsets).
#define AH_OFF   0ull          // f16 [16384][1024]  (xt | m), row = t*64+b
#define DLH_OFF  8388608ull    // f16 [16384][512]   Dl
#define DH_OFF   12582912ull   // f32 [16384][512]   delta_h
#define GP_OFF   20971520ull   // f16 [16384][2048]  G_pre
#define WCT_OFF  37748736ull   // f16 [2048][1024]   gate W (x|m), col-major rows
#define GHT_OFF  38797312ull   // f16 [512][512]     gh_W transposed
#define WHT_OFF  38928384ull   // f16 [2048][512]    gate W h-part, col-major rows
#define BC_OFF   39452672ull   // f32 [2048]
#define HS_OFF   39454720ull   // uint [2][4 groups][4096] frag-linear h exchange
#define FLG_OFF  39487488ull   // int [32] flags (4 groups x 8, packed)

typedef _Float16 h8_t __attribute__((ext_vector_type(8)));
typedef _Float16 h4_t __attribute__((ext_vector_type(4)));
typedef float f32x4 __attribute__((ext_vector_type(4)));
typedef unsigned long long ull2_t __attribute__((ext_vector_type(2)));

typedef const __attribute__((address_space(1))) void* gas_p;
typedef __attribute__((address_space(3))) void* las_p;

__device__ __forceinline__ float fast_exp2(float x) {
#if defined(__has_builtin)
#if __has_builtin(__builtin_amdgcn_exp2f)
  return __builtin_amdgcn_exp2f(x);
#else
  return exp2f(x);
#endif
#else
  return exp2f(x);
#endif
}
__device__ __forceinline__ float fast_rcp(float x) {
#if defined(__has_builtin)
#if __has_builtin(__builtin_amdgcn_rcpf)
  return __builtin_amdgcn_rcpf(x);
#else
  return 1.0f / x;
#endif
#else
  return 1.0f / x;
#endif
}
#define LOG2E 1.4426950408889634f
__device__ __forceinline__ float sigmoidf_(float v) {
  return fast_rcp(1.0f + fast_exp2(-LOG2E * v));
}
__device__ __forceinline__ float tanhf_(float v) {
  return 1.0f - 2.0f * fast_rcp(1.0f + fast_exp2(2.0f * LOG2E * v));
}

// ---------------------------------------------------------------------------
// Repack:
//   WCT f16 [2048][1024]: WCT[4j+g][k<512]=Wg[k][j] (x), [512+k]=Wg[1024+k][j] (m)
//   WHT f16 [2048][512] :  WHT[4j+g][k] = Wg[512+k][j]
//   GHT f16 [512][512]  :  GHT[j][k] = ghW[k][j]
//   BC  f32 [2048]
// ---------------------------------------------------------------------------
__global__ __launch_bounds__(256) void repack_kernel(
    const float* __restrict__ Wi, const float* __restrict__ bi,
    const float* __restrict__ Wf, const float* __restrict__ bff,
    const float* __restrict__ Wo, const float* __restrict__ bo,
    const float* __restrict__ Wc, const float* __restrict__ bc,
    const float* __restrict__ ghW,
    __half* __restrict__ WCT, __half* __restrict__ WHT,
    __half* __restrict__ GHT, float* __restrict__ BC) {
  int idx = blockIdx.x * 256 + threadIdx.x;  // 512*512
  int k = idx >> 9, j = idx & 511;
  const float* Ws[4] = {Wi, Wf, Wo, Wc};
  const float* bs[4] = {bi, bff, bo, bc};
#pragma unroll
  for (int g = 0; g < 4; ++g) {
    const float* W = Ws[g];
    int col = j * 4 + g;
    WCT[(size_t)col * 1024 + k] = __float2half(W[(size_t)k * 512 + j]);
    WCT[(size_t)col * 1024 + 512 + k] = __float2half(W[(size_t)(1024 + k) * 512 + j]);
    WHT[(size_t)col * 512 + k] = __float2half(W[(size_t)(512 + k) * 512 + j]);
    if (k == 0) BC[col] = bs[g][j];
  }
  GHT[(size_t)j * 512 + k] = __float2half(ghW[(size_t)k * 512 + j]);
}

// ---------------------------------------------------------------------------
// xt: AH[r][d] = xt (f16), AH[r][512+d] = m (f16), DLh[r][d] = dl (f16)
// x layout: [B][4][T][D]; 0=X,1=Xl,2=M,3=Dl ; r = t*64+b
// ---------------------------------------------------------------------------
__global__ __launch_bounds__(256) void xt_kernel(
    const float* __restrict__ x, const float* __restrict__ Xmean,
    const float* __restrict__ gxw, const float* __restrict__ gxb,
    __half* __restrict__ AH, __half* __restrict__ DLh) {
  int idx = blockIdx.x * 256 + threadIdx.x;
  int d = (idx & 127) * 4;
  int r = idx >> 7;
  int b = r & 63, t = r >> 6;
  size_t base = (((size_t)b * 4) * TT + t) * DD + d;
  const float4 X = *(const float4*)&x[base];
  const float4 Xl = *(const float4*)&x[base + (size_t)TT * DD];
  const float4 M = *(const float4*)&x[base + 2ull * TT * DD];
  const float4 Dl = *(const float4*)&x[base + 3ull * TT * DD];
  const float4 xm = *(const float4*)&Xmean[(size_t)t * DD + d];
  const float4 gw = *(const float4*)&gxw[d];
  const float4 gb = *(const float4*)&gxb[d];
  float o[4];
  {
    float dx = fast_exp2(-LOG2E * fmaxf(0.f, Dl.x * gw.x + gb.x));
    o[0] = M.x * X.x + (1.f - M.x) * (dx * Xl.x + (1.f - dx) * xm.x);
  }
  {
    float dx = fast_exp2(-LOG2E * fmaxf(0.f, Dl.y * gw.y + gb.y));
    o[1] = M.y * X.y + (1.f - M.y) * (dx * Xl.y + (1.f - dx) * xm.y);
  }
  {
    float dx = fast_exp2(-LOG2E * fmaxf(0.f, Dl.z * gw.z + gb.z));
    o[2] = M.z * X.z + (1.f - M.z) * (dx * Xl.z + (1.f - dx) * xm.z);
  }
  {
    float dx = fast_exp2(-LOG2E * fmaxf(0.f, Dl.w * gw.w + gb.w));
    o[3] = M.w * X.w + (1.f - M.w) * (dx * Xl.w + (1.f - dx) * xm.w);
  }
  h4_t xo = {(_Float16)o[0], (_Float16)o[1], (_Float16)o[2], (_Float16)o[3]};
  h4_t mo = {(_Float16)M.x, (_Float16)M.y, (_Float16)M.z, (_Float16)M.w};
  h4_t dlo = {(_Float16)Dl.x, (_Float16)Dl.y, (_Float16)Dl.z, (_Float16)Dl.w};
  *(h4_t*)&AH[(size_t)r * 1024 + d] = xo;
  *(h4_t*)&AH[(size_t)r * 1024 + 512 + d] = mo;
  *(h4_t*)&DLh[(size_t)r * 512 + d] = dlo;
}

// ---------------------------------------------------------------------------
// f16 MFMA GEMM, m97 structure: 128x128 tile, 256 threads, K-step 32,
// linear LDS [128][32] staged via global_load_lds width=16 (4 issues/thread).
// mode 0: C f16. mode 1: C f32, exp(-relu(v)).  (proven correct rounds 1/4)
// ---------------------------------------------------------------------------
__global__ __launch_bounds__(256, 2) void gemm16(
    const __half* __restrict__ A, const __half* __restrict__ BT,
    const float* __restrict__ bias, void* __restrict__ C,
    int K, int Ncols, int mode) {
  __shared__ _Float16 Ash[128 * 32];
  __shared__ _Float16 Bsh[128 * 32];
  const int tid = threadIdx.x;
  const int lane = tid & 63, w = tid >> 6;
  const int l15 = lane & 15, quad = lane >> 4;
  const int wr = w >> 1, wc = w & 1;
  const int row0 = blockIdx.y * 128, col0 = blockIdx.x * 128;

  f32x4 acc[4][4] = {};

  // staging chunk ci covers LDS bytes [ci*16, ci*16+16) == row ci>>2, halves (ci&3)*8
  const int ci0 = tid, ci1 = 256 + tid;
  const int ar0 = ci0 >> 2, ac0 = (ci0 & 3) * 8;
  const int ar1 = ci1 >> 2, ac1 = (ci1 & 3) * 8;
  const __half* Abase = A + (size_t)row0 * K;
  const __half* Bbase = BT + (size_t)col0 * K;

  for (int k0 = 0; k0 < K; k0 += 32) {
    __syncthreads();  // previous tile's readers done
    __builtin_amdgcn_global_load_lds((gas_p)(Abase + (size_t)ar0 * K + k0 + ac0),
                                     (las_p)(Ash + ci0 * 8), 16, 0, 0);
    __builtin_amdgcn_global_load_lds((gas_p)(Abase + (size_t)ar1 * K + k0 + ac1),
                                     (las_p)(Ash + ci1 * 8), 16, 0, 0);
    __builtin_amdgcn_global_load_lds((gas_p)(Bbase + (size_t)ar0 * K + k0 + ac0),
                                     (las_p)(Bsh + ci0 * 8), 16, 0, 0);
    __builtin_amdgcn_global_load_lds((gas_p)(Bbase + (size_t)ar1 * K + k0 + ac1),
                                     (las_p)(Bsh + ci1 * 8), 16, 0, 0);
    __syncthreads();  // vmcnt(0) drain -> tiles resident
    h8_t af[4], bf[4];
#pragma unroll
    for (int mt = 0; mt < 4; ++mt)
      af[mt] = *(const h8_t*)&Ash[(wr * 64 + mt * 16 + l15) * 32 + quad * 8];
#pragma unroll
    for (int ct = 0; ct < 4; ++ct)
      bf[ct] = *(const h8_t*)&Bsh[(wc * 64 + ct * 16 + l15) * 32 + quad * 8];
#pragma unroll
    for (int mt = 0; mt < 4; ++mt)
#pragma unroll
      for (int ct = 0; ct < 4; ++ct)
        acc[mt][ct] = __builtin_amdgcn_mfma_f32_16x16x32_f16(af[mt], bf[ct], acc[mt][ct], 0, 0, 0);
  }

#pragma unroll
  for (int ct = 0; ct < 4; ++ct) {
    const int col = col0 + wc * 64 + ct * 16 + l15;
    const float bv = bias[col];
#pragma unroll
    for (int mt = 0; mt < 4; ++mt) {
#pragma unroll
      for (int reg = 0; reg < 4; ++reg) {
        const int row = row0 + wr * 64 + mt * 16 + quad * 4 + reg;
        float v = acc[mt][ct][reg] + bv;
        if (mode == 0) {
          ((__half*)C)[(size_t)row * Ncols + col] = __float2half(v);
        } else {
          ((float*)C)[(size_t)row * Ncols + col] = fast_exp2(-LOG2E * fmaxf(0.f, v));
        }
      }
    }
  }
}

// ---------------------------------------------------------------------------
// Recurrence: 32 blocks x 512 threads, cooperative. 4 groups of 8 blocks.
// Group g owns rows [16g,16g+16); member m owns gate cols [256m,256m+256).
// PROTOCOL = round-0 exactly (hardware-proven): 2 __syncthreads/step,
// exchange+out stores before the vm-drain barrier, tid0 flag after it,
// per-block flags, 8-flag poll, s_sleep backoff, double-buffered HS slots.
//
// This round's consumer-side changes (traffic/residency only):
//  1. LDS staging of the group's 16KB A-slot, once per BLOCK (was: every
//     wave loaded the full 16KB from fabric -> 64x same-line fan-out/group).
//     Each thread: 4 x 8B agent loads -> LDS; frags via ds_read_b128.
//  2. Single-wave poll: wave 0 polls the 8 flags, __syncthreads releases the
//     block (was: all 8 waves hammering the same flag line).
//  3. amdgpu_waves_per_eu(2,2): grid is 32 blocks (1/CU), so allow 256 VGPRs
//     -> bfrag[2][16] (128 VGPRs) stays register-resident instead of being
//     re-loaded (32KB/wave of WHT) every step. 512-thr block needs 2
//     waves/SIMD => cap 256 stays launchable.
//  GPh/DH epilogue loads issue at the top of the iteration: in flight across
//  poll+staging, retired long before the epilogue uses them.
// ---------------------------------------------------------------------------
__global__ __launch_bounds__(512)
__attribute__((amdgpu_waves_per_eu(2, 2))) void persist_rnn(
    const __half* __restrict__ GPh, const float* __restrict__ DH,
    const __half* __restrict__ WHT, unsigned* __restrict__ hs,
    int* __restrict__ flg, float* __restrict__ out) {
  __shared__ __align__(16) float gbuf[16 * 260];
  __shared__ __align__(16) unsigned long long stag[2048];  // 16KB A-slot mirror
  const int g = blockIdx.x & 3;   // group
  const int m = blockIdx.x >> 2;  // member 0..7
  const int tid = threadIdx.x;
  const int lane = tid & 63;
  const int w = tid >> 6;
  const int l15 = lane & 15;
  const int quad = lane >> 4;
  const int rowg0 = g << 4;

  // ---- B fragments, loaded once (register-resident at 256-VGPR budget) ----
  h8_t bfrag[2][16];
  const int colbase = (m << 8) + (w << 5);
#pragma unroll
  for (int nt = 0; nt < 2; ++nt) {
#pragma unroll
    for (int kt = 0; kt < 16; ++kt) {
      int col = colbase + nt * 16 + l15;
      int k = kt * 32 + quad * 8;
      bfrag[nt][kt] = *(const h8_t*)&WHT[(size_t)col * 512 + k];
    }
  }

  const int r_ep = w;
  const int ug = (m << 6) + lane;
  // frag-layout dest uint indices for the two h stores (even lanes use them)
  const int ktu = ug >> 5, q3 = (ug >> 3) & 3, qi = (ug & 7) >> 1;
  const int d0 = ktu * 256 + (q3 * 16 + r_ep) * 4 + qi;
  const int d1 = ktu * 256 + (q3 * 16 + r_ep + 8) * 4 + qi;

  float c0 = 0.f, c1 = 0.f;

  for (int t = 0; t < TT; ++t) {
    // ---- epilogue operand loads for THIS step: in flight across poll+stage
    const h4_t gha = *(const h4_t*)&GPh[((size_t)t * 64 + rowg0 + r_ep) * NC + (ug << 2)];
    const h4_t ghb = *(const h4_t*)&GPh[((size_t)t * 64 + rowg0 + r_ep + 8) * NC + (ug << 2)];
    const int tn = (t + 1 < TT) ? t + 1 : t;
    const float dha = DH[((size_t)tn * 64 + rowg0 + r_ep) * HH + ug];
    const float dhb = DH[((size_t)tn * 64 + rowg0 + r_ep + 8) * HH + ug];

    // ---- single-wave poll, barrier release ----
    if (t > 0) {
      if (w == 0) {
        const int* fb = flg + (g << 3);
        for (;;) {
          int v = __hip_atomic_load(&fb[lane & 7], __ATOMIC_RELAXED,
                                    __HIP_MEMORY_SCOPE_AGENT);
          if (__all(v >= t)) break;
          __builtin_amdgcn_s_sleep(1);
        }
      }
      __syncthreads();
    }

    // ---- stage the group's 16KB frag-linear slot into LDS (once/block) ----
    const unsigned long long* hsp =
        (const unsigned long long*)hs + ((size_t)(t & 1) * 4 + g) * 2048;
    unsigned long long sv0 = __hip_atomic_load(&hsp[tid], __ATOMIC_RELAXED,
                                               __HIP_MEMORY_SCOPE_AGENT);
    unsigned long long sv1 = __hip_atomic_load(&hsp[tid + 512], __ATOMIC_RELAXED,
                                               __HIP_MEMORY_SCOPE_AGENT);
    unsigned long long sv2 = __hip_atomic_load(&hsp[tid + 1024], __ATOMIC_RELAXED,
                                               __HIP_MEMORY_SCOPE_AGENT);
    unsigned long long sv3 = __hip_atomic_load(&hsp[tid + 1536], __ATOMIC_RELAXED,
                                               __HIP_MEMORY_SCOPE_AGENT);
    stag[tid] = sv0;
    stag[tid + 512] = sv1;
    stag[tid + 1024] = sv2;
    stag[tid + 1536] = sv3;
    __syncthreads();

    // ---- A fragments from LDS ----
    h8_t af[16];
#pragma unroll
    for (int kt = 0; kt < 16; ++kt) {
      ull2_t u2 = *(const ull2_t*)&stag[kt * 128 + lane * 2];
      af[kt] = __builtin_bit_cast(h8_t, u2);
    }

    // ---- MFMA ----
    f32x4 acc0 = {0.f, 0.f, 0.f, 0.f};
    f32x4 acc1 = {0.f, 0.f, 0.f, 0.f};
#pragma unroll
    for (int kt = 0; kt < 16; ++kt) {
      acc0 = __builtin_amdgcn_mfma_f32_16x16x32_f16(af[kt], bfrag[0][kt], acc0, 0, 0, 0);
      acc1 = __builtin_amdgcn_mfma_f32_16x16x32_f16(af[kt], bfrag[1][kt], acc1, 0, 0, 0);
    }
#pragma unroll
    for (int reg = 0; reg < 4; ++reg) {
      int row = quad * 4 + reg;
      gbuf[row * 260 + (w << 5) + l15] = acc0[reg];
      gbuf[row * 260 + (w << 5) + 16 + l15] = acc1[reg];
    }
    __syncthreads();

    // ---- epilogue: rows r_ep, r_ep+8 ; unit ug ----
    float h0v, h1v;
    {
      const float4 gv = *(const float4*)&gbuf[r_ep * 260 + (lane << 2)];
      float ig = sigmoidf_(gv.x + (float)gha[0]);
      float fg = sigmoidf_(gv.y + (float)gha[1]);
      float og = sigmoidf_(gv.z + (float)gha[2]);
      float ct = tanhf_(gv.w + (float)gha[3]);
      c0 = fg * c0 + ig * ct;
      h0v = og * tanhf_(c0);
    }
    {
      const float4 gv = *(const float4*)&gbuf[(r_ep + 8) * 260 + (lane << 2)];
      float ig = sigmoidf_(gv.x + (float)ghb[0]);
      float fg = sigmoidf_(gv.y + (float)ghb[1]);
      float og = sigmoidf_(gv.z + (float)ghb[2]);
      float ct = tanhf_(gv.w + (float)ghb[3]);
      c1 = fg * c1 + ig * ct;
      h1v = og * tanhf_(c1);
    }

    // ---- exchange + out stores BEFORE the drain (round-0 position) ----
    if (t + 1 < TT) {
      unsigned* hsn = hs + ((size_t)((t + 1) & 1) * 4 + g) * 4096;
      unsigned short hb0 = __half_as_ushort(__float2half(dha * h0v));
      unsigned o0 = (unsigned)__shfl_xor((int)(unsigned)hb0, 1) & 0xffffu;
      unsigned short hb1 = __half_as_ushort(__float2half(dhb * h1v));
      unsigned o1 = (unsigned)__shfl_xor((int)(unsigned)hb1, 1) & 0xffffu;
      if (!(lane & 1)) {
        __hip_atomic_store(&hsn[d0], (unsigned)hb0 | (o0 << 16), __ATOMIC_RELAXED,
                           __HIP_MEMORY_SCOPE_AGENT);
        __hip_atomic_store(&hsn[d1], (unsigned)hb1 | (o1 << 16), __ATOMIC_RELAXED,
                           __HIP_MEMORY_SCOPE_AGENT);
      }
    }
    out[((size_t)(rowg0 + r_ep) * TT + t) * HH + ug] = h0v;
    out[((size_t)(rowg0 + r_ep + 8) * TT + t) * HH + ug] = h1v;

    // ---- vm-drain barrier, then publish flag ----
    __syncthreads();  // compiler emits s_waitcnt vmcnt(0) per wave before barrier
    if (t + 1 < TT && tid == 0)
      __hip_atomic_store(&flg[(g << 3) + m], t + 1, __ATOMIC_RELAXED,
                         __HIP_MEMORY_SCOPE_AGENT);
  }
}

// ---------------------------------------------------------------------------
extern "C" void kernel_launch(void* const* d_in, const int* in_sizes, int n_in,
                              void* d_out, int out_size, void* d_ws,
                              size_t ws_size, hipStream_t stream) {
  const float* x = (const float*)d_in[0];
  const float* Xmean = (const float*)d_in[1];
  const float* Wi = (const float*)d_in[2];
  const float* bi = (const float*)d_in[3];
  const float* Wf = (const float*)d_in[4];
  const float* bf = (const float*)d_in[5];
  const float* Wo = (const float*)d_in[6];
  const float* bo = (const float*)d_in[7];
  const float* Wc = (const float*)d_in[8];
  const float* bc = (const float*)d_in[9];
  const float* gxw = (const float*)d_in[10];
  const float* gxb = (const float*)d_in[11];
  const float* ghW = (const float*)d_in[12];
  const float* ghb = (const float*)d_in[13];
  float* out = (float*)d_out;
  float* ws = (float*)d_ws;

  __half* AH = (__half*)(ws + AH_OFF);
  __half* DLh = (__half*)(ws + DLH_OFF);
  float* DH = ws + DH_OFF;
  __half* GPh = (__half*)(ws + GP_OFF);
  __half* WCT = (__half*)(ws + WCT_OFF);
  __half* GHT = (__half*)(ws + GHT_OFF);
  __half* WHT = (__half*)(ws + WHT_OFF);
  float* BC = ws + BC_OFF;
  unsigned* HS = (unsigned*)(ws + HS_OFF);
  int* FLG = (int*)(ws + FLG_OFF);

  // zero h exchange buffers + flags (ws poisoned each launch)
  hipMemsetAsync(HS, 0, (2ull * 4 * 4096 + 64) * sizeof(unsigned), stream);

  repack_kernel<<<1024, 256, 0, stream>>>(Wi, bi, Wf, bf, Wo, bo, Wc, bc, ghW,
                                          WCT, WHT, GHT, BC);
  xt_kernel<<<8192, 256, 0, stream>>>(x, Xmean, gxw, gxb, AH, DLh);
  // DH = exp(-relu(Dl @ ghW + ghb)) : M=16384, N=512, K=512
  gemm16<<<dim3(4, 128), 256, 0, stream>>>(DLh, GHT, ghb, (void*)DH, 512, 512, 1);
  // GP = [xt|m] @ [Wx;Wm] + BC : M=16384, N=2048, K=1024 (f16 out)
  gemm16<<<dim3(16, 128), 256, 0, stream>>>(AH, WCT, BC, (void*)GPh, 1024, NC, 0);

  void* args[] = {(void*)&GPh, (void*)&DH, (void*)&WHT,
                  (void*)&HS, (void*)&FLG, (void*)&out};
  hipLaunchCooperativeKernel((const void*)persist_rnn, dim3(32), dim3(512),
                             args, 0, stream);
}

// Round 6
// 1043.960 us; speedup vs baseline: 2.0570x; 1.0023x over previous
//
#include <hip/hip_runtime.h>
#include <hip/hip_fp16.h>
#include <math.h>

// Problem dims
#define TT 256
#define BB 64
#define DD 512
#define HH 512
#define NC 2048  // 4 gates * H, col = j*4+g (g: 0=i,1=f,2=o,3=ctilde)

// Workspace layout (float-slot offsets).
#define AH_OFF   0ull          // f16 [16384][1024]  (xt | m), row = t*64+b
#define DLH_OFF  8388608ull    // f16 [16384][512]   Dl
#define DH_OFF   12582912ull   // f32 [16384][512]   delta_h
#define GP_OFF   20971520ull   // f16 [16384][2048]  G_pre
#define WCT_OFF  37748736ull   // f16 [2048][1024]   gate W (x|m), col-major rows
#define GHT_OFF  38797312ull   // f16 [512][512]     gh_W transposed
#define WHT_OFF  38928384ull   // f16 [2048][512]    gate W h-part, col-major rows
#define BC_OFF   39452672ull   // f32 [2048]
#define HS_OFF   39454720ull   // uint [2][4 groups][4096] frag-linear h exchange
#define FLG_OFF  39487488ull   // int [4 groups][16] flags, 64B line per group

typedef _Float16 h8_t __attribute__((ext_vector_type(8)));
typedef _Float16 h4_t __attribute__((ext_vector_type(4)));
typedef float f32x4 __attribute__((ext_vector_type(4)));
typedef unsigned long long ull2_t __attribute__((ext_vector_type(2)));

typedef const __attribute__((address_space(1))) void* gas_p;
typedef __attribute__((address_space(3))) void* las_p;

__device__ __forceinline__ float fast_exp2(float x) {
#if defined(__has_builtin)
#if __has_builtin(__builtin_amdgcn_exp2f)
  return __builtin_amdgcn_exp2f(x);
#else
  return exp2f(x);
#endif
#else
  return exp2f(x);
#endif
}
__device__ __forceinline__ float fast_rcp(float x) {
#if defined(__has_builtin)
#if __has_builtin(__builtin_amdgcn_rcpf)
  return __builtin_amdgcn_rcpf(x);
#else
  return 1.0f / x;
#endif
#else
  return 1.0f / x;
#endif
}
#define LOG2E 1.4426950408889634f
__device__ __forceinline__ float sigmoidf_(float v) {
  return fast_rcp(1.0f + fast_exp2(-LOG2E * v));
}
__device__ __forceinline__ float tanhf_(float v) {
  return 1.0f - 2.0f * fast_rcp(1.0f + fast_exp2(2.0f * LOG2E * v));
}

// ---------------------------------------------------------------------------
// Repack:
//   WCT f16 [2048][1024]: WCT[4j+g][k<512]=Wg[k][j] (x), [512+k]=Wg[1024+k][j] (m)
//   WHT f16 [2048][512] :  WHT[4j+g][k] = Wg[512+k][j]
//   GHT f16 [512][512]  :  GHT[j][k] = ghW[k][j]
//   BC  f32 [2048]
// ---------------------------------------------------------------------------
__global__ __launch_bounds__(256) void repack_kernel(
    const float* __restrict__ Wi, const float* __restrict__ bi,
    const float* __restrict__ Wf, const float* __restrict__ bff,
    const float* __restrict__ Wo, const float* __restrict__ bo,
    const float* __restrict__ Wc, const float* __restrict__ bc,
    const float* __restrict__ ghW,
    __half* __restrict__ WCT, __half* __restrict__ WHT,
    __half* __restrict__ GHT, float* __restrict__ BC) {
  int idx = blockIdx.x * 256 + threadIdx.x;  // 512*512
  int k = idx >> 9, j = idx & 511;
  const float* Ws[4] = {Wi, Wf, Wo, Wc};
  const float* bs[4] = {bi, bff, bo, bc};
#pragma unroll
  for (int g = 0; g < 4; ++g) {
    const float* W = Ws[g];
    int col = j * 4 + g;
    WCT[(size_t)col * 1024 + k] = __float2half(W[(size_t)k * 512 + j]);
    WCT[(size_t)col * 1024 + 512 + k] = __float2half(W[(size_t)(1024 + k) * 512 + j]);
    WHT[(size_t)col * 512 + k] = __float2half(W[(size_t)(512 + k) * 512 + j]);
    if (k == 0) BC[col] = bs[g][j];
  }
  GHT[(size_t)j * 512 + k] = __float2half(ghW[(size_t)k * 512 + j]);
}

// ---------------------------------------------------------------------------
// xt: AH[r][d] = xt (f16), AH[r][512+d] = m (f16), DLh[r][d] = dl (f16)
// x layout: [B][4][T][D]; 0=X,1=Xl,2=M,3=Dl ; r = t*64+b
// ---------------------------------------------------------------------------
__global__ __launch_bounds__(256) void xt_kernel(
    const float* __restrict__ x, const float* __restrict__ Xmean,
    const float* __restrict__ gxw, const float* __restrict__ gxb,
    __half* __restrict__ AH, __half* __restrict__ DLh) {
  int idx = blockIdx.x * 256 + threadIdx.x;
  int d = (idx & 127) * 4;
  int r = idx >> 7;
  int b = r & 63, t = r >> 6;
  size_t base = (((size_t)b * 4) * TT + t) * DD + d;
  const float4 X = *(const float4*)&x[base];
  const float4 Xl = *(const float4*)&x[base + (size_t)TT * DD];
  const float4 M = *(const float4*)&x[base + 2ull * TT * DD];
  const float4 Dl = *(const float4*)&x[base + 3ull * TT * DD];
  const float4 xm = *(const float4*)&Xmean[(size_t)t * DD + d];
  const float4 gw = *(const float4*)&gxw[d];
  const float4 gb = *(const float4*)&gxb[d];
  float o[4];
  {
    float dx = fast_exp2(-LOG2E * fmaxf(0.f, Dl.x * gw.x + gb.x));
    o[0] = M.x * X.x + (1.f - M.x) * (dx * Xl.x + (1.f - dx) * xm.x);
  }
  {
    float dx = fast_exp2(-LOG2E * fmaxf(0.f, Dl.y * gw.y + gb.y));
    o[1] = M.y * X.y + (1.f - M.y) * (dx * Xl.y + (1.f - dx) * xm.y);
  }
  {
    float dx = fast_exp2(-LOG2E * fmaxf(0.f, Dl.z * gw.z + gb.z));
    o[2] = M.z * X.z + (1.f - M.z) * (dx * Xl.z + (1.f - dx) * xm.z);
  }
  {
    float dx = fast_exp2(-LOG2E * fmaxf(0.f, Dl.w * gw.w + gb.w));
    o[3] = M.w * X.w + (1.f - M.w) * (dx * Xl.w + (1.f - dx) * xm.w);
  }
  h4_t xo = {(_Float16)o[0], (_Float16)o[1], (_Float16)o[2], (_Float16)o[3]};
  h4_t mo = {(_Float16)M.x, (_Float16)M.y, (_Float16)M.z, (_Float16)M.w};
  h4_t dlo = {(_Float16)Dl.x, (_Float16)Dl.y, (_Float16)Dl.z, (_Float16)Dl.w};
  *(h4_t*)&AH[(size_t)r * 1024 + d] = xo;
  *(h4_t*)&AH[(size_t)r * 1024 + 512 + d] = mo;
  *(h4_t*)&DLh[(size_t)r * 512 + d] = dlo;
}

// ---------------------------------------------------------------------------
// f16 MFMA GEMM, m97 structure: 128x128 tile, 256 threads, K-step 32,
// linear LDS [128][32] staged via global_load_lds width=16 (4 issues/thread).
// mode 0: C f16. mode 1: C f32, exp(-relu(v)).  (proven correct rounds 1/4/5)
// ---------------------------------------------------------------------------
__global__ __launch_bounds__(256, 2) void gemm16(
    const __half* __restrict__ A, const __half* __restrict__ BT,
    const float* __restrict__ bias, void* __restrict__ C,
    int K, int Ncols, int mode) {
  __shared__ _Float16 Ash[128 * 32];
  __shared__ _Float16 Bsh[128 * 32];
  const int tid = threadIdx.x;
  const int lane = tid & 63, w = tid >> 6;
  const int l15 = lane & 15, quad = lane >> 4;
  const int wr = w >> 1, wc = w & 1;
  const int row0 = blockIdx.y * 128, col0 = blockIdx.x * 128;

  f32x4 acc[4][4] = {};

  // staging chunk ci covers LDS bytes [ci*16, ci*16+16) == row ci>>2, halves (ci&3)*8
  const int ci0 = tid, ci1 = 256 + tid;
  const int ar0 = ci0 >> 2, ac0 = (ci0 & 3) * 8;
  const int ar1 = ci1 >> 2, ac1 = (ci1 & 3) * 8;
  const __half* Abase = A + (size_t)row0 * K;
  const __half* Bbase = BT + (size_t)col0 * K;

  for (int k0 = 0; k0 < K; k0 += 32) {
    __syncthreads();  // previous tile's readers done
    __builtin_amdgcn_global_load_lds((gas_p)(Abase + (size_t)ar0 * K + k0 + ac0),
                                     (las_p)(Ash + ci0 * 8), 16, 0, 0);
    __builtin_amdgcn_global_load_lds((gas_p)(Abase + (size_t)ar1 * K + k0 + ac1),
                                     (las_p)(Ash + ci1 * 8), 16, 0, 0);
    __builtin_amdgcn_global_load_lds((gas_p)(Bbase + (size_t)ar0 * K + k0 + ac0),
                                     (las_p)(Bsh + ci0 * 8), 16, 0, 0);
    __builtin_amdgcn_global_load_lds((gas_p)(Bbase + (size_t)ar1 * K + k0 + ac1),
                                     (las_p)(Bsh + ci1 * 8), 16, 0, 0);
    __syncthreads();  // vmcnt(0) drain -> tiles resident
    h8_t af[4], bf[4];
#pragma unroll
    for (int mt = 0; mt < 4; ++mt)
      af[mt] = *(const h8_t*)&Ash[(wr * 64 + mt * 16 + l15) * 32 + quad * 8];
#pragma unroll
    for (int ct = 0; ct < 4; ++ct)
      bf[ct] = *(const h8_t*)&Bsh[(wc * 64 + ct * 16 + l15) * 32 + quad * 8];
#pragma unroll
    for (int mt = 0; mt < 4; ++mt)
#pragma unroll
      for (int ct = 0; ct < 4; ++ct)
        acc[mt][ct] = __builtin_amdgcn_mfma_f32_16x16x32_f16(af[mt], bf[ct], acc[mt][ct], 0, 0, 0);
  }

#pragma unroll
  for (int ct = 0; ct < 4; ++ct) {
    const int col = col0 + wc * 64 + ct * 16 + l15;
    const float bv = bias[col];
#pragma unroll
    for (int mt = 0; mt < 4; ++mt) {
#pragma unroll
      for (int reg = 0; reg < 4; ++reg) {
        const int row = row0 + wr * 64 + mt * 16 + quad * 4 + reg;
        float v = acc[mt][ct][reg] + bv;
        if (mode == 0) {
          ((__half*)C)[(size_t)row * Ncols + col] = __float2half(v);
        } else {
          ((float*)C)[(size_t)row * Ncols + col] = fast_exp2(-LOG2E * fmaxf(0.f, v));
        }
      }
    }
  }
}

// ---------------------------------------------------------------------------
// Recurrence: 32 blocks x 512 threads, cooperative. 4 groups of 8 blocks.
// Group g owns rows [16g,16g+16); member m owns gate cols [256m,256m+256).
// PROTOCOL = round-0/round-5 (hardware-proven): single-wave flag poll ->
// barrier release; block-wide LDS staging of the group's 16KB A-slot;
// 2 more __syncthreads/step; exchange+out stores before the vm-drain
// barrier; tid0 flag after it; s_sleep backoff; double-buffered HS slots.
//
// This round:
//  1. bfrag KEEPALIVE (rule-17): round-5 counters proved bfrag[2][16] was NOT
//     register-resident (VGPR_Count=96 < 128 needed) -- LLVM rematerializes
//     the read-only WHT loads every step => 256KB/block/step L2 stream inside
//     the MFMA dependence chain. The empty asm "+v" on each fragment inside
//     the t-loop makes them non-rematerializable, forcing residency
//     (~230 VGPRs <= 256 budget from waves_per_eu(2,2); 8 waves x 256 = full
//     2048-reg file = 1 block/CU, exactly our 32-block grid).
//  2. Flag padding: per-group flags on their own 64B line (flg[g*16+m]) --
//     no cross-group false sharing on the poll line.
// ---------------------------------------------------------------------------
__global__ __launch_bounds__(512)
__attribute__((amdgpu_waves_per_eu(2, 2))) void persist_rnn(
    const __half* __restrict__ GPh, const float* __restrict__ DH,
    const __half* __restrict__ WHT, unsigned* __restrict__ hs,
    int* __restrict__ flg, float* __restrict__ out) {
  __shared__ __align__(16) float gbuf[16 * 260];
  __shared__ __align__(16) unsigned long long stag[2048];  // 16KB A-slot mirror
  const int g = blockIdx.x & 3;   // group
  const int m = blockIdx.x >> 2;  // member 0..7
  const int tid = threadIdx.x;
  const int lane = tid & 63;
  const int w = tid >> 6;
  const int l15 = lane & 15;
  const int quad = lane >> 4;
  const int rowg0 = g << 4;

  // ---- B fragments, loaded once; keepalive in-loop forces residency ----
  h8_t bfrag[2][16];
  const int colbase = (m << 8) + (w << 5);
#pragma unroll
  for (int nt = 0; nt < 2; ++nt) {
#pragma unroll
    for (int kt = 0; kt < 16; ++kt) {
      int col = colbase + nt * 16 + l15;
      int k = kt * 32 + quad * 8;
      bfrag[nt][kt] = *(const h8_t*)&WHT[(size_t)col * 512 + k];
    }
  }

  const int r_ep = w;
  const int ug = (m << 6) + lane;
  // frag-layout dest uint indices for the two h stores (even lanes use them)
  const int ktu = ug >> 5, q3 = (ug >> 3) & 3, qi = (ug & 7) >> 1;
  const int d0 = ktu * 256 + (q3 * 16 + r_ep) * 4 + qi;
  const int d1 = ktu * 256 + (q3 * 16 + r_ep + 8) * 4 + qi;

  float c0 = 0.f, c1 = 0.f;

  for (int t = 0; t < TT; ++t) {
    // ---- keepalive: mark bfrag as asm-redefined each iteration so the
    // allocator cannot rematerialize the WHT loads per step (rule-17) ----
#pragma unroll
    for (int nt = 0; nt < 2; ++nt)
#pragma unroll
      for (int kt = 0; kt < 16; ++kt)
        asm volatile("" : "+v"(bfrag[nt][kt]));

    // ---- epilogue operand loads for THIS step: in flight across poll+stage
    const h4_t gha = *(const h4_t*)&GPh[((size_t)t * 64 + rowg0 + r_ep) * NC + (ug << 2)];
    const h4_t ghb = *(const h4_t*)&GPh[((size_t)t * 64 + rowg0 + r_ep + 8) * NC + (ug << 2)];
    const int tn = (t + 1 < TT) ? t + 1 : t;
    const float dha = DH[((size_t)tn * 64 + rowg0 + r_ep) * HH + ug];
    const float dhb = DH[((size_t)tn * 64 + rowg0 + r_ep + 8) * HH + ug];

    // ---- single-wave poll, barrier release ----
    if (t > 0) {
      if (w == 0) {
        const int* fb = flg + (g << 4);
        for (;;) {
          int v = __hip_atomic_load(&fb[lane & 7], __ATOMIC_RELAXED,
                                    __HIP_MEMORY_SCOPE_AGENT);
          if (__all(v >= t)) break;
          __builtin_amdgcn_s_sleep(1);
        }
      }
      __syncthreads();
    }

    // ---- stage the group's 16KB frag-linear slot into LDS (once/block) ----
    const unsigned long long* hsp =
        (const unsigned long long*)hs + ((size_t)(t & 1) * 4 + g) * 2048;
    unsigned long long sv0 = __hip_atomic_load(&hsp[tid], __ATOMIC_RELAXED,
                                               __HIP_MEMORY_SCOPE_AGENT);
    unsigned long long sv1 = __hip_atomic_load(&hsp[tid + 512], __ATOMIC_RELAXED,
                                               __HIP_MEMORY_SCOPE_AGENT);
    unsigned long long sv2 = __hip_atomic_load(&hsp[tid + 1024], __ATOMIC_RELAXED,
                                               __HIP_MEMORY_SCOPE_AGENT);
    unsigned long long sv3 = __hip_atomic_load(&hsp[tid + 1536], __ATOMIC_RELAXED,
                                               __HIP_MEMORY_SCOPE_AGENT);
    stag[tid] = sv0;
    stag[tid + 512] = sv1;
    stag[tid + 1024] = sv2;
    stag[tid + 1536] = sv3;
    __syncthreads();

    // ---- A fragments from LDS ----
    h8_t af[16];
#pragma unroll
    for (int kt = 0; kt < 16; ++kt) {
      ull2_t u2 = *(const ull2_t*)&stag[kt * 128 + lane * 2];
      af[kt] = __builtin_bit_cast(h8_t, u2);
    }

    // ---- MFMA ----
    f32x4 acc0 = {0.f, 0.f, 0.f, 0.f};
    f32x4 acc1 = {0.f, 0.f, 0.f, 0.f};
#pragma unroll
    for (int kt = 0; kt < 16; ++kt) {
      acc0 = __builtin_amdgcn_mfma_f32_16x16x32_f16(af[kt], bfrag[0][kt], acc0, 0, 0, 0);
      acc1 = __builtin_amdgcn_mfma_f32_16x16x32_f16(af[kt], bfrag[1][kt], acc1, 0, 0, 0);
    }
#pragma unroll
    for (int reg = 0; reg < 4; ++reg) {
      int row = quad * 4 + reg;
      gbuf[row * 260 + (w << 5) + l15] = acc0[reg];
      gbuf[row * 260 + (w << 5) + 16 + l15] = acc1[reg];
    }
    __syncthreads();

    // ---- epilogue: rows r_ep, r_ep+8 ; unit ug ----
    float h0v, h1v;
    {
      const float4 gv = *(const float4*)&gbuf[r_ep * 260 + (lane << 2)];
      float ig = sigmoidf_(gv.x + (float)gha[0]);
      float fg = sigmoidf_(gv.y + (float)gha[1]);
      float og = sigmoidf_(gv.z + (float)gha[2]);
      float ct = tanhf_(gv.w + (float)gha[3]);
      c0 = fg * c0 + ig * ct;
      h0v = og * tanhf_(c0);
    }
    {
      const float4 gv = *(const float4*)&gbuf[(r_ep + 8) * 260 + (lane << 2)];
      float ig = sigmoidf_(gv.x + (float)ghb[0]);
      float fg = sigmoidf_(gv.y + (float)ghb[1]);
      float og = sigmoidf_(gv.z + (float)ghb[2]);
      float ct = tanhf_(gv.w + (float)ghb[3]);
      c1 = fg * c1 + ig * ct;
      h1v = og * tanhf_(c1);
    }

    // ---- exchange + out stores BEFORE the drain (round-0 position) ----
    if (t + 1 < TT) {
      unsigned* hsn = hs + ((size_t)((t + 1) & 1) * 4 + g) * 4096;
      unsigned short hb0 = __half_as_ushort(__float2half(dha * h0v));
      unsigned o0 = (unsigned)__shfl_xor((int)(unsigned)hb0, 1) & 0xffffu;
      unsigned short hb1 = __half_as_ushort(__float2half(dhb * h1v));
      unsigned o1 = (unsigned)__shfl_xor((int)(unsigned)hb1, 1) & 0xffffu;
      if (!(lane & 1)) {
        __hip_atomic_store(&hsn[d0], (unsigned)hb0 | (o0 << 16), __ATOMIC_RELAXED,
                           __HIP_MEMORY_SCOPE_AGENT);
        __hip_atomic_store(&hsn[d1], (unsigned)hb1 | (o1 << 16), __ATOMIC_RELAXED,
                           __HIP_MEMORY_SCOPE_AGENT);
      }
    }
    out[((size_t)(rowg0 + r_ep) * TT + t) * HH + ug] = h0v;
    out[((size_t)(rowg0 + r_ep + 8) * TT + t) * HH + ug] = h1v;

    // ---- vm-drain barrier, then publish flag ----
    __syncthreads();  // compiler emits s_waitcnt vmcnt(0) per wave before barrier
    if (t + 1 < TT && tid == 0)
      __hip_atomic_store(&flg[(g << 4) + m], t + 1, __ATOMIC_RELAXED,
                         __HIP_MEMORY_SCOPE_AGENT);
  }
}

// ---------------------------------------------------------------------------
extern "C" void kernel_launch(void* const* d_in, const int* in_sizes, int n_in,
                              void* d_out, int out_size, void* d_ws,
                              size_t ws_size, hipStream_t stream) {
  const float* x = (const float*)d_in[0];
  const float* Xmean = (const float*)d_in[1];
  const float* Wi = (const float*)d_in[2];
  const float* bi = (const float*)d_in[3];
  const float* Wf = (const float*)d_in[4];
  const float* bf = (const float*)d_in[5];
  const float* Wo = (const float*)d_in[6];
  const float* bo = (const float*)d_in[7];
  const float* Wc = (const float*)d_in[8];
  const float* bc = (const float*)d_in[9];
  const float* gxw = (const float*)d_in[10];
  const float* gxb = (const float*)d_in[11];
  const float* ghW = (const float*)d_in[12];
  const float* ghb = (const float*)d_in[13];
  float* out = (float*)d_out;
  float* ws = (float*)d_ws;

  __half* AH = (__half*)(ws + AH_OFF);
  __half* DLh = (__half*)(ws + DLH_OFF);
  float* DH = ws + DH_OFF;
  __half* GPh = (__half*)(ws + GP_OFF);
  __half* WCT = (__half*)(ws + WCT_OFF);
  __half* GHT = (__half*)(ws + GHT_OFF);
  __half* WHT = (__half*)(ws + WHT_OFF);
  float* BC = ws + BC_OFF;
  unsigned* HS = (unsigned*)(ws + HS_OFF);
  int* FLG = (int*)(ws + FLG_OFF);

  // zero h exchange buffers + 64 flag slots (ws poisoned each launch)
  hipMemsetAsync(HS, 0, (2ull * 4 * 4096 + 64) * sizeof(unsigned), stream);

  repack_kernel<<<1024, 256, 0, stream>>>(Wi, bi, Wf, bf, Wo, bo, Wc, bc, ghW,
                                          WCT, WHT, GHT, BC);
  xt_kernel<<<8192, 256, 0, stream>>>(x, Xmean, gxw, gxb, AH, DLh);
  // DH = exp(-relu(Dl @ ghW + ghb)) : M=16384, N=512, K=512
  gemm16<<<dim3(4, 128), 256, 0, stream>>>(DLh, GHT, ghb, (void*)DH, 512, 512, 1);
  // GP = [xt|m] @ [Wx;Wm] + BC : M=16384, N=2048, K=1024 (f16 out)
  gemm16<<<dim3(16, 128), 256, 0, stream>>>(AH, WCT, BC, (void*)GPh, 1024, NC, 0);

  void* args[] = {(void*)&GPh, (void*)&DH, (void*)&WHT,
                  (void*)&HS, (void*)&FLG, (void*)&out};
  hipLaunchCooperativeKernel((const void*)persist_rnn, dim3(32), dim3(512),
                             args, 0, stream);
}